// Round 1
// baseline (104.367 us; speedup 1.0000x reference)
//
#include <hip/hip_runtime.h>
#include <math.h>

#define NN 2048
#define CC 64
#define SS 128
#define KK 8

// RADIUS_NDC = 1.5/128*2 = 0.0234375 (exact);  R2 = 9/16384 (exact)
#define R2f      0.00054931640625f
#define INV_R2f  (1.0f / 0.00054931640625f)

__global__ __launch_bounds__(256, 2) void raster_composite_kernel(
    const float* __restrict__ pts3D,  // [B, N, 3]
    const float* __restrict__ src,    // [B, C, N]
    float* __restrict__ out)          // [B, C, S, S]
{
    // LDS: points phase: sXY[2*NN] (x,y interleaved, sign-flipped), sZ[NN]
    //      merge phase (reuse): zM[32*64], dM[32*64], iM[32*64]  (same 24KB)
    __shared__ float sP[3 * NN];
    __shared__ float sW[KK * 64];
    __shared__ int   sI[KK * 64];

    const int tid   = threadIdx.x;
    const int blk   = blockIdx.x;       // B * 128 * 2 = 512 blocks
    const int b     = blk >> 8;         // 256 strips per batch
    const int strip = blk & 255;
    const int gy    = strip >> 1;       // row 0..127
    const int xbase = (strip & 1) * 64; // half-row

    const int lx    = tid & 63;         // pixel within strip
    const int chunk = tid >> 6;         // 0..3 point chunk / channel group
    const int gx    = xbase + lx;

    // ---- Phase 0: load points into LDS (SoA, sign-flip x,y) ----
    const float* P = pts3D + (size_t)b * NN * 3;
    for (int i = tid; i < NN * 3; i += 256) {
        float v = P[i];
        int pt = i / 3;
        int comp = i - pt * 3;
        float s = (comp == 2) ? v : -v;
        int addr = (comp == 2) ? (2 * NN + pt) : (2 * pt + comp);
        sP[addr] = s;
    }
    __syncthreads();

    // pixel centers, pytorch3d convention (exact: /128 is pow2)
    const float pcx = 1.0f - (2.0f * (float)gx + 1.0f) / (float)SS;
    const float pcy = 1.0f - (2.0f * (float)gy + 1.0f) / (float)SS;

    // ---- Phase 1: scan my 512-point chunk, keep top-8 smallest z ----
    float bz[KK], bd[KK];
    int   bi[KK];
#pragma unroll
    for (int j = 0; j < KK; ++j) { bz[j] = INFINITY; bd[j] = 0.0f; bi[j] = 0; }

    const int i0 = chunk * (NN / 4);
#pragma unroll 4
    for (int t = 0; t < NN / 4; ++t) {
        int i = i0 + t;
        float2 xy = *reinterpret_cast<const float2*>(&sP[2 * i]); // wave-uniform -> broadcast
        float z = sP[2 * NN + i];
        float dx = pcx - xy.x;
        float dy = pcy - xy.y;
        float d2 = dy * dy + dx * dx;
        if (d2 < R2f && z > 0.0f && z < bz[KK - 1]) {
            // stable sorted insert (strict <): ties keep lower index first, like top_k
            float iz = z, id2 = d2; int ii = i;
#pragma unroll
            for (int j = 0; j < KK; ++j) {
                if (iz < bz[j]) {
                    float tz = bz[j], td = bd[j]; int ti = bi[j];
                    bz[j] = iz; bd[j] = id2; bi[j] = ii;
                    iz = tz; id2 = td; ii = ti;
                }
            }
        }
    }
    __syncthreads();  // done with point LDS; reuse for merge

    // ---- Phase 2a: publish partial lists; layout [entry(32)][lane(64)] ----
    float* zM = sP;
    float* dM = sP + 32 * 64;
    int*   iM = (int*)(sP + 2 * 32 * 64);
    {
        const int ebase = chunk * KK;
#pragma unroll
        for (int j = 0; j < KK; ++j) {
            zM[(ebase + j) * 64 + lx] = bz[j];
            dM[(ebase + j) * 64 + lx] = bd[j];
            iM[(ebase + j) * 64 + lx] = bi[j];
        }
    }
    __syncthreads();

    // ---- Phase 2b: 4-way merge + alpha/compositing weights (1 thread/pixel) ----
    if (tid < 64) {
        const int p = tid;
        int head0 = 0, head1 = 0, head2 = 0, head3 = 0;
        float T = 1.0f;
#pragma unroll
        for (int k = 0; k < KK; ++k) {
            float best = INFINITY; int bc = -1;
            // scan chunks in order: strict < keeps lowest chunk (lowest index) on ties
            {
                float zc;
                if (head0 < KK) { zc = zM[(0 * KK + head0) * 64 + p]; if (zc < best) { best = zc; bc = 0; } }
                if (head1 < KK) { zc = zM[(1 * KK + head1) * 64 + p]; if (zc < best) { best = zc; bc = 1; } }
                if (head2 < KK) { zc = zM[(2 * KK + head2) * 64 + p]; if (zc < best) { best = zc; bc = 2; } }
                if (head3 < KK) { zc = zM[(3 * KK + head3) * 64 + p]; if (zc < best) { best = zc; bc = 3; } }
            }
            float w = 0.0f; int id = 0;
            if (bc >= 0) {
                int h = (bc == 0) ? head0 : (bc == 1) ? head1 : (bc == 2) ? head2 : head3;
                int e = (bc * KK + h) * 64 + p;
                float d2 = dM[e];
                id = iM[e];
                if (bc == 0) head0++; else if (bc == 1) head1++; else if (bc == 2) head2++; else head3++;
                float dn = d2 * INV_R2f;
                dn = fminf(fmaxf(dn, 0.001f), 1.0f);
                float a = 1.0f - sqrtf(dn);   // tau = 1
                w = a * T;
                T *= (1.0f - a);
            }
            sW[k * 64 + p] = w;
            sI[k * 64 + p] = id;
        }
    }
    __syncthreads();

    // ---- Phase 3: gather features, accumulate, store ----
    float w[KK]; int id[KK];
#pragma unroll
    for (int k = 0; k < KK; ++k) {
        w[k]  = sW[k * 64 + lx];
        id[k] = sI[k * 64 + lx];
    }

    const float* F = src + (size_t)b * CC * NN;
    float* O = out + (size_t)b * CC * SS * SS + (size_t)gy * SS + gx;
#pragma unroll 4
    for (int cc = 0; cc < CC / 4; ++cc) {
        int c = chunk * (CC / 4) + cc;
        const float* Fc = F + (size_t)c * NN;
        float acc = 0.0f;
#pragma unroll
        for (int k = 0; k < KK; ++k) acc += w[k] * Fc[id[k]];
        O[(size_t)c * SS * SS] = acc;
    }
}

extern "C" void kernel_launch(void* const* d_in, const int* in_sizes, int n_in,
                              void* d_out, int out_size, void* d_ws, size_t ws_size,
                              hipStream_t stream) {
    const float* pts3D = (const float*)d_in[0]; // [2,2048,3]
    const float* src   = (const float*)d_in[1]; // [2,64,2048]
    float* out = (float*)d_out;                 // [2,64,128,128]
    (void)in_sizes; (void)n_in; (void)out_size; (void)d_ws; (void)ws_size;
    raster_composite_kernel<<<dim3(512), dim3(256), 0, stream>>>(pts3D, src, out);
}

// Round 2
// 77.811 us; speedup vs baseline: 1.3413x; 1.3413x over previous
//
#include <hip/hip_runtime.h>
#include <math.h>

#define NN 2048
#define CC 64
#define SS 128
#define KK 8
#define CAP 16
#define NPIX (2 * SS * SS)   /* 32768 pixels total (B=2) */

// RADIUS_NDC = 1.5/128*2 = 0.0234375 (exact dyadic); R2 = 9/16384 (exact)
#define R2f 0.00054931640625f

// ---------------- Pass 1: scatter points into per-pixel bins ----------------
// One thread per (b, n). Each point's 1.5px disk covers <=4x4 pixel centers.
// Append packed key (z_bits<<32 | idx) — ascending u64 order == (z, idx)
// lexicographic == jax.lax.top_k's smallest-z / lowest-index-tie order.
__global__ void bin_points_kernel(const float* __restrict__ pts3D,
                                  int* __restrict__ cnt,
                                  unsigned long long* __restrict__ ent) {
    int t = blockIdx.x * 256 + threadIdx.x;
    if (t >= 2 * NN) return;
    int b = t >> 11;
    int n = t & (NN - 1);
    const float* p = pts3D + (size_t)t * 3;
    float x = -p[0], y = -p[1], z = p[2];   // forward's sign flip
    if (!(z > 0.0f)) return;

    // pixel center i satisfies |pix(i)-x| < R  <=>  i in (fc-1.5, fc+1.5),
    // fc = 64*(1-x) - 0.5   (64*R = 1.5 px). Boundary-inclusive is safe:
    // the strict d2 < R2 test below is authoritative.
    float fcx = 64.0f * (1.0f - x) - 0.5f;
    float fcy = 64.0f * (1.0f - y) - 0.5f;
    int ix0 = max((int)ceilf(fcx - 1.5f), 0);
    int ix1 = min((int)floorf(fcx + 1.5f), SS - 1);
    int iy0 = max((int)ceilf(fcy - 1.5f), 0);
    int iy1 = min((int)floorf(fcy + 1.5f), SS - 1);

    unsigned long long key =
        ((unsigned long long)__float_as_uint(z) << 32) | (unsigned)n;

    for (int iy = iy0; iy <= iy1; ++iy) {
        float pcy = 1.0f - (2.0f * (float)iy + 1.0f) * (1.0f / (float)SS);
        float dy = pcy - y;
        float dy2 = dy * dy;
        for (int ix = ix0; ix <= ix1; ++ix) {
            float pcx = 1.0f - (2.0f * (float)ix + 1.0f) * (1.0f / (float)SS);
            float dx = pcx - x;
            float dx2 = dx * dx;
            float d2 = dy2 + dx2;           // same order as reference (dy2+dx2)
            if (d2 < R2f) {
                int pix = (b << 14) | (iy << 7) | ix;
                int slot = atomicAdd(&cnt[pix], 1);
                if (slot < CAP)
                    ent[(size_t)pix * CAP + slot] = key;
            }
        }
    }
}

// ---------------- Pass 2: per-pixel sort + alpha-composite + gather ----------------
// Block: 256 threads = 32 consecutive pixels x 8 channel-groups (8 ch each).
// Stores coalesce along the pixel dimension.
__global__ __launch_bounds__(256) void composite_kernel(
    const float* __restrict__ pts3D,
    const float* __restrict__ src,
    const int* __restrict__ cnt,
    const unsigned long long* __restrict__ ent,
    float* __restrict__ out) {
    const int tid = threadIdx.x;
    const int lx = tid & 31;       // pixel within block
    const int cg = tid >> 5;       // channel group 0..7
    const int gpix = blockIdx.x * 32 + lx;   // 0..NPIX-1
    const int b = gpix >> 14;
    const int pixin = gpix & 16383;
    const int iy = pixin >> 7;
    const int ix = pixin & (SS - 1);

    float* O = out + (size_t)b * CC * (SS * SS) + pixin;

    int c_raw = cnt[gpix];
    int cn = c_raw < CAP ? c_raw : CAP;

    if (cn == 0) {   // ~41% of pixels: pure zero-fill
#pragma unroll
        for (int cc = 0; cc < CC / 8; ++cc)
            O[(size_t)(cg * 8 + cc) * (SS * SS)] = 0.0f;
        return;
    }

    // top-8 smallest keys, ascending (static-index shift chain -> stays in VGPRs)
    const unsigned long long SENT = ~0ULL;
    unsigned long long s[KK];
#pragma unroll
    for (int j = 0; j < KK; ++j) s[j] = SENT;
    const unsigned long long* ep = ent + (size_t)gpix * CAP;
    for (int i = 0; i < cn; ++i) {
        unsigned long long k = ep[i];
        if (k < s[KK - 1]) {
#pragma unroll
            for (int j = 0; j < KK; ++j) {
                if (k < s[j]) { unsigned long long t = s[j]; s[j] = k; k = t; }
            }
        }
    }

    // weights: alpha = 1 - sqrt(clip(d2/R2, 1e-3, 1)); front-to-back T
    const float pcx = 1.0f - (2.0f * (float)ix + 1.0f) * (1.0f / (float)SS);
    const float pcy = 1.0f - (2.0f * (float)iy + 1.0f) * (1.0f / (float)SS);
    float w[KK];
    int id[KK];
    float T = 1.0f;
#pragma unroll
    for (int k = 0; k < KK; ++k) {
        w[k] = 0.0f;
        id[k] = 0;
        if (s[k] != SENT) {
            int n = (int)(unsigned)(s[k] & 0xffffffffu);
            id[k] = n;
            const float* p = pts3D + (size_t)(b * NN + n) * 3;
            float x = -p[0], y = -p[1];
            float dx = pcx - x, dy = pcy - y;
            float dx2 = dx * dx, dy2 = dy * dy;
            float d2 = dy2 + dx2;
            float dn = d2 / R2f;
            dn = fminf(fmaxf(dn, 0.001f), 1.0f);
            float a = 1.0f - sqrtf(dn);   // tau = 1
            w[k] = a * T;
            T *= (1.0f - a);
        }
    }

    // gather features (src 1MB -> L2-resident), accumulate, coalesced store
    const float* F = src + (size_t)b * CC * NN;
#pragma unroll
    for (int cc = 0; cc < CC / 8; ++cc) {
        int c = cg * 8 + cc;
        const float* Fc = F + (size_t)c * NN;
        float acc = 0.0f;
#pragma unroll
        for (int k = 0; k < KK; ++k) acc += w[k] * Fc[id[k]];
        O[(size_t)c * (SS * SS)] = acc;
    }
}

extern "C" void kernel_launch(void* const* d_in, const int* in_sizes, int n_in,
                              void* d_out, int out_size, void* d_ws, size_t ws_size,
                              hipStream_t stream) {
    const float* pts3D = (const float*)d_in[0]; // [2,2048,3]
    const float* src   = (const float*)d_in[1]; // [2,64,2048]
    float* out = (float*)d_out;                 // [2,64,128,128]
    (void)in_sizes; (void)n_in; (void)out_size; (void)ws_size;

    int* cnt = (int*)d_ws;                                   // 128 KB
    unsigned long long* ent =
        (unsigned long long*)((char*)d_ws + NPIX * sizeof(int)); // 4 MB

    hipMemsetAsync(d_ws, 0, NPIX * sizeof(int), stream);
    bin_points_kernel<<<(2 * NN + 255) / 256, 256, 0, stream>>>(pts3D, cnt, ent);
    composite_kernel<<<NPIX / 32, 256, 0, stream>>>(pts3D, src, cnt, ent, out);
}

// Round 3
// 73.954 us; speedup vs baseline: 1.4112x; 1.0521x over previous
//
#include <hip/hip_runtime.h>
#include <math.h>

#define NN 2048
#define CC 64
#define SS 128
#define KK 8
#define TCAP 128          /* candidate cap per 2x32 tile; E[cand]~22, 23 sigma headroom */

// RADIUS_NDC = 1.5/128*2 = 3/128 (exact dyadic); R2 = 9/16384 (exact)
#define R2f    0.00054931640625f
#define RNDCf  0.0234375f

// One fused kernel: per-block tile binning (LDS) -> per-pixel top-8 z-sort ->
// alpha compositing -> feature gather. Tile = 2 rows x 32 cols of pixels.
// Grid = B * 64 tile-rows * 4 tile-cols = 512 blocks.
__global__ __launch_bounds__(256) void raster_fused_kernel(
    const float* __restrict__ pts3D,  // [B, N, 3]
    const float* __restrict__ src,    // [B, C, N]
    float* __restrict__ out)          // [B, C, S, S]
{
    __shared__ float scx[TCAP];
    __shared__ float scy[TCAP];
    __shared__ unsigned long long skey[TCAP];
    __shared__ int scount;
    __shared__ float sW[KK * 64];
    __shared__ int   sI[KK * 64];

    const int tid = threadIdx.x;
    const int blk = blockIdx.x;          // 512
    const int b   = blk >> 8;
    const int tb  = blk & 255;
    const int Y0  = (tb >> 2) * 2;       // tile: rows Y0..Y0+1
    const int X0  = (tb & 3) * 32;       // cols X0..X0+31

    if (tid == 0) scount = 0;
    __syncthreads();

    // ---- Phase A: bin points whose 1.5px disk can touch this tile ----
    // pixel centers p(i) = 1 - (2i+1)/128 decrease with i (exact dyadic)
    const float cxmax = 1.0f - (2.0f * (float)X0 + 1.0f) / (float)SS;
    const float cxmin = 1.0f - (2.0f * (float)(X0 + 31) + 1.0f) / (float)SS;
    const float cymax = 1.0f - (2.0f * (float)Y0 + 1.0f) / (float)SS;
    const float cymin = 1.0f - (2.0f * (float)(Y0 + 1) + 1.0f) / (float)SS;
    const float Rm = RNDCf + 1e-6f;      // inclusive margin; strict test is authoritative

    const float* P = pts3D + (size_t)b * NN * 3;
#pragma unroll
    for (int j = 0; j < NN / 256; ++j) {
        int n = tid + j * 256;
        const float* p = P + (size_t)n * 3;
        float x = -p[0], y = -p[1], z = p[2];   // forward's sign flip
        if (z > 0.0f &&
            x >= cxmin - Rm && x <= cxmax + Rm &&
            y >= cymin - Rm && y <= cymax + Rm) {
            int slot = atomicAdd(&scount, 1);
            if (slot < TCAP) {
                scx[slot] = x;
                scy[slot] = y;
                // ascending u64 == (z, idx) lexicographic == top_k order (idx unique -> no ties)
                skey[slot] = ((unsigned long long)__float_as_uint(z) << 32) | (unsigned)n;
            }
        }
    }
    __syncthreads();
    const int cn = min(scount, TCAP);

    // ---- Phase B: per-pixel top-8 by key, alpha/transmittance weights ----
    if (tid < 64) {
        const int col = tid & 31, r = tid >> 5;
        const int ix = X0 + col, iy = Y0 + r;
        const float pcx = 1.0f - (2.0f * (float)ix + 1.0f) / (float)SS;
        const float pcy = 1.0f - (2.0f * (float)iy + 1.0f) / (float)SS;

        const unsigned long long SENT = ~0ULL;
        unsigned long long s[KK];
        float sd[KK];
#pragma unroll
        for (int j = 0; j < KK; ++j) { s[j] = SENT; sd[j] = 0.0f; }

        for (int i = 0; i < cn; ++i) {   // LDS broadcast reads (wave-uniform addr)
            float dx = pcx - scx[i];
            float dy = pcy - scy[i];
            float d2 = dy * dy + dx * dx;      // same op order as reference (dy2+dx2)
            unsigned long long k = skey[i];
            if (d2 < R2f && k < s[KK - 1]) {
                float dd = d2;
#pragma unroll
                for (int j = 0; j < KK; ++j) {
                    if (k < s[j]) {
                        unsigned long long tk = s[j]; s[j] = k; k = tk;
                        float td = sd[j]; sd[j] = dd; dd = td;
                    }
                }
            }
        }

        float T = 1.0f;
#pragma unroll
        for (int k = 0; k < KK; ++k) {
            float w = 0.0f; int id = 0;
            if (s[k] != SENT) {
                id = (int)(unsigned)(s[k] & 0xffffffffu);
                float dn = sd[k] / R2f;        // ref: dist_sel / RADIUS_NDC**2
                dn = fminf(fmaxf(dn, 0.001f), 1.0f);
                float a = 1.0f - sqrtf(dn);    // tau = 1
                w = a * T;
                T *= (1.0f - a);
            }
            sW[k * 64 + tid] = w;
            sI[k * 64 + tid] = id;
        }
    }
    __syncthreads();

    // ---- Phase C: feature gather + coalesced store (4 ch-groups x 64 px) ----
    const int px = tid & 63;
    const int cg = tid >> 6;     // 0..3 -> 16 channels each
    float w[KK]; int id[KK];
#pragma unroll
    for (int k = 0; k < KK; ++k) {
        w[k]  = sW[k * 64 + px];   // stride-1 across lanes: conflict-free
        id[k] = sI[k * 64 + px];
    }
    const int col = px & 31, r = px >> 5;
    float* O = out + (size_t)b * CC * (SS * SS) + (size_t)(Y0 + r) * SS + (X0 + col);
    const float* F = src + (size_t)b * CC * NN;
#pragma unroll 4
    for (int cc = 0; cc < CC / 4; ++cc) {
        int c = cg * (CC / 4) + cc;
        const float* Fc = F + (size_t)c * NN;
        float acc = 0.0f;
#pragma unroll
        for (int k = 0; k < KK; ++k) acc += w[k] * Fc[id[k]];
        O[(size_t)c * (SS * SS)] = acc;   // per c: 2 rows x 32 floats = 128B segments
    }
}

extern "C" void kernel_launch(void* const* d_in, const int* in_sizes, int n_in,
                              void* d_out, int out_size, void* d_ws, size_t ws_size,
                              hipStream_t stream) {
    const float* pts3D = (const float*)d_in[0]; // [2,2048,3]
    const float* src   = (const float*)d_in[1]; // [2,64,2048]
    float* out = (float*)d_out;                 // [2,64,128,128]
    (void)in_sizes; (void)n_in; (void)out_size; (void)d_ws; (void)ws_size;

    raster_fused_kernel<<<dim3(512), dim3(256), 0, stream>>>(pts3D, src, out);
}

// Round 4
// 71.945 us; speedup vs baseline: 1.4507x; 1.0279x over previous
//
#include <hip/hip_runtime.h>
#include <math.h>

#define NN 2048
#define CC 64
#define SS 128
#define KK 8
#define TCAP 128          /* candidate cap per 2x32 tile; E[cn]~22 */

// RADIUS_NDC = 1.5/128*2 = 3/128 (exact dyadic); R2 = 9/16384 (exact dyadic)
#define R2f    0.00054931640625f
#define RNDCf  0.0234375f

// Fused raster+composite. Tile = 2 rows x 32 cols of pixels; each tile is
// handled by TWO blocks (channel halves) for occupancy. Grid = 1024 blocks:
// blk = b(1) | ty(6) | tx(2) | half(1).
// Pipeline per block:
//   A: bin points vs tile apron bbox into LDS (atomic append, unordered)
//   S: rank-sort candidates by u64 (z_bits, idx) key (unique -> total order
//      == jax.lax.top_k's smallest-z, lowest-index-tie order; deterministic
//      despite atomic append order)
//   B: per-pixel front-to-back online pass: first 8 strict d2<R2 hits in
//      ascending-key order ARE the top-8; transmittance updated online.
//   C: per (pixel, 8-channel-group) weighted feature gather, coalesced store.
__global__ __launch_bounds__(256, 4) void raster_fused_kernel(
    const float* __restrict__ pts3D,  // [B, N, 3]
    const float* __restrict__ src,    // [B, C, N]
    float* __restrict__ out)          // [B, C, S, S]
{
    __shared__ float scx[TCAP], scy[TCAP];
    __shared__ unsigned long long skey[TCAP];
    __shared__ float ssx[TCAP], ssy[TCAP];
    __shared__ int   sid[TCAP];
    __shared__ int   scount;
    __shared__ float sW[KK * 64];
    __shared__ int   sI[KK * 64];

    const int tid  = threadIdx.x;
    const int blk  = blockIdx.x;        // 1024
    const int half = blk & 1;           // channel half: c in [half*32, half*32+32)
    const int X0   = ((blk >> 1) & 3) * 32;
    const int Y0   = ((blk >> 3) & 63) * 2;
    const int b    = blk >> 9;

    if (tid == 0) scount = 0;
    sW[tid] = 0.0f; sW[tid + 256] = 0.0f;   // empty slots -> w=0, id=0 (safe)
    sI[tid] = 0;    sI[tid + 256] = 0;
    __syncthreads();

    // ---- Phase A: bin points whose 1.5px disk can touch this tile ----
    // pixel centers p(i) = 1 - (2i+1)/128 (exact dyadic), decreasing in i
    const float cxmax = 1.0f - (2.0f * (float)X0 + 1.0f) / (float)SS;
    const float cxmin = 1.0f - (2.0f * (float)(X0 + 31) + 1.0f) / (float)SS;
    const float cymax = 1.0f - (2.0f * (float)Y0 + 1.0f) / (float)SS;
    const float cymin = 1.0f - (2.0f * (float)(Y0 + 1) + 1.0f) / (float)SS;
    const float Rm = RNDCf + 1e-6f;   // inclusive margin; strict d2<R2 is authoritative

    const float* P = pts3D + (size_t)b * NN * 3;
#pragma unroll
    for (int j = 0; j < NN / 256; ++j) {
        int n = tid + j * 256;
        float x = -P[n * 3 + 0], y = -P[n * 3 + 1], z = P[n * 3 + 2];
        if (z > 0.0f &&
            x >= cxmin - Rm && x <= cxmax + Rm &&
            y >= cymin - Rm && y <= cymax + Rm) {
            int slot = atomicAdd(&scount, 1);
            if (slot < TCAP) {
                scx[slot] = x;
                scy[slot] = y;
                skey[slot] = ((unsigned long long)__float_as_uint(z) << 32) | (unsigned)n;
            }
        }
    }
    __syncthreads();
    const int cn = min(scount, TCAP);

    // ---- Phase S: rank-sort by key (ascending). Keys unique -> bijective ranks ----
    if (tid < cn) {
        unsigned long long mykey = skey[tid];
        int rank = 0;
        for (int j = 0; j < cn; ++j)           // wave-uniform j -> LDS broadcast
            rank += (skey[j] < mykey) ? 1 : 0;
        ssx[rank] = scx[tid];
        ssy[rank] = scy[tid];
        sid[rank] = (int)(unsigned)(mykey & 0xffffffffu);
    }
    __syncthreads();

    // ---- Phase B: per-pixel online front-to-back composite weights ----
    if (tid < 64) {
        const int col = tid & 31, r = tid >> 5;
        const float pcx = 1.0f - (2.0f * (float)(X0 + col) + 1.0f) / (float)SS;
        const float pcy = 1.0f - (2.0f * (float)(Y0 + r) + 1.0f) / (float)SS;
        float T = 1.0f;
        int cnt = 0;
        for (int i = 0; i < cn; ++i) {
            float dx = pcx - ssx[i];           // broadcast LDS reads
            float dy = pcy - ssy[i];
            float d2 = dy * dy + dx * dx;      // ref op order (dy2+dx2)
            if (d2 < R2f && cnt < KK) {
                float dn = d2 / R2f;           // ref: dist_sel / RADIUS_NDC**2
                dn = fminf(fmaxf(dn, 0.001f), 1.0f);
                float a = 1.0f - sqrtf(dn);    // tau = 1
                sW[cnt * 64 + tid] = a * T;
                sI[cnt * 64 + tid] = sid[i];
                T *= (1.0f - a);
                ++cnt;
            }
        }
    }
    __syncthreads();

    // ---- Phase C: weighted feature gather + coalesced store (half channels) ----
    const int px = tid & 63;
    const int cg = tid >> 6;                    // 0..3 -> 8 channels each
    float w[KK]; int id[KK];
#pragma unroll
    for (int k = 0; k < KK; ++k) {
        w[k]  = sW[k * 64 + px];                // stride-1 lanes: conflict-free
        id[k] = sI[k * 64 + px];
    }
    const int col = px & 31, r = px >> 5;
    float* O = out + (size_t)b * CC * (SS * SS) + (size_t)(Y0 + r) * SS + (X0 + col);
    const float* F = src + (size_t)b * CC * NN;
#pragma unroll
    for (int cc = 0; cc < 8; ++cc) {
        int c = half * 32 + cg * 8 + cc;
        const float* Fc = F + (size_t)c * NN;
        float acc = 0.0f;
#pragma unroll
        for (int k = 0; k < KK; ++k) acc += w[k] * Fc[id[k]];
        O[(size_t)c * (SS * SS)] = acc;         // 2 rows x 32 floats = 128B segs
    }
}

extern "C" void kernel_launch(void* const* d_in, const int* in_sizes, int n_in,
                              void* d_out, int out_size, void* d_ws, size_t ws_size,
                              hipStream_t stream) {
    const float* pts3D = (const float*)d_in[0]; // [2,2048,3]
    const float* src   = (const float*)d_in[1]; // [2,64,2048]
    float* out = (float*)d_out;                 // [2,64,128,128]
    (void)in_sizes; (void)n_in; (void)out_size; (void)d_ws; (void)ws_size;

    raster_fused_kernel<<<dim3(1024), dim3(256), 0, stream>>>(pts3D, src, out);
}

// Round 5
// 65.586 us; speedup vs baseline: 1.5913x; 1.0969x over previous
//
#include <hip/hip_runtime.h>
#include <math.h>

#define NN 2048
#define CC 64
#define SS 128
#define KK 8
#define TCAP 128          /* candidate cap per 2x32 tile; E[cn]~22, P(overflow)~0 */
#define FPAD 33           /* sF slot stride: (slot*33+c)%32=(slot+c)%32 -> conflict-free */

// RADIUS_NDC = 1.5/128*2 = 3/128 (exact dyadic); R2 = 9/16384 (exact dyadic)
#define R2f    0.00054931640625f
#define RNDCf  0.0234375f

// Fused raster+composite. Tile = 2 rows x 32 cols of pixels; each tile handled
// by TWO blocks (channel halves). Grid = 1024: blk = b(1)|ty(6)|tx(2)|half(1).
//   A: bin points vs tile apron bbox into LDS (atomic append, unordered)
//   S: rank-sort candidates by u64 (z_bits, idx) key (unique -> total order ==
//      jax.lax.top_k smallest-z / lowest-index-tie order)
//   B (wave 0) : per-pixel online front-to-back pass — first 8 strict d2<R2
//      hits in ascending-key order ARE the top-8; transmittance online.
//   G (waves 1-3, concurrent with B): gather candidate feature rows into LDS
//      (~22 coalesced loads/block instead of 16K scattered L2 gathers).
//   C: per (pixel, channel-group) weighted accumulate from LDS, coalesced store.
__global__ __launch_bounds__(256, 4) void raster_fused_kernel(
    const float* __restrict__ pts3D,  // [B, N, 3]
    const float* __restrict__ src,    // [B, C, N]
    float* __restrict__ out)          // [B, C, S, S]
{
    __shared__ float scx[TCAP], scy[TCAP];
    __shared__ unsigned long long skey[TCAP];
    __shared__ float ssx[TCAP], ssy[TCAP];
    __shared__ int   sid[TCAP];           // sorted slot -> global point idx
    __shared__ int   scount;
    __shared__ float sW[KK * 64];
    __shared__ int   sS[KK * 64];         // per-pixel selected slot
    __shared__ float sF[TCAP * FPAD];     // candidate features (this half's 32 ch)

    const int tid  = threadIdx.x;
    const int blk  = blockIdx.x;          // 1024
    const int half = blk & 1;             // channels [half*32, half*32+32)
    const int X0   = ((blk >> 1) & 3) * 32;
    const int Y0   = ((blk >> 3) & 63) * 2;
    const int b    = blk >> 9;

    if (tid == 0) scount = 0;
    sW[tid] = 0.0f; sW[tid + 256] = 0.0f;   // empty slots -> w=0, slot=0 (safe)
    sS[tid] = 0;    sS[tid + 256] = 0;
    __syncthreads();

    // ---- Phase A: bin points whose 1.5px disk can touch this tile ----
    const float cxmax = 1.0f - (2.0f * (float)X0 + 1.0f) / (float)SS;
    const float cxmin = 1.0f - (2.0f * (float)(X0 + 31) + 1.0f) / (float)SS;
    const float cymax = 1.0f - (2.0f * (float)Y0 + 1.0f) / (float)SS;
    const float cymin = 1.0f - (2.0f * (float)(Y0 + 1) + 1.0f) / (float)SS;
    const float Rm = RNDCf + 1e-6f;   // inclusive margin; strict d2<R2 authoritative

    const float* P = pts3D + (size_t)b * NN * 3;
#pragma unroll
    for (int j = 0; j < NN / 256; ++j) {
        int n = tid + j * 256;
        float x = -P[n * 3 + 0], y = -P[n * 3 + 1], z = P[n * 3 + 2];
        if (z > 0.0f &&
            x >= cxmin - Rm && x <= cxmax + Rm &&
            y >= cymin - Rm && y <= cymax + Rm) {
            int slot = atomicAdd(&scount, 1);
            if (slot < TCAP) {
                scx[slot] = x;
                scy[slot] = y;
                skey[slot] = ((unsigned long long)__float_as_uint(z) << 32) | (unsigned)n;
            }
        }
    }
    __syncthreads();
    const int cn = min(scount, TCAP);

    // ---- Phase S: rank-sort by key ascending (keys unique -> bijective) ----
    if (tid < cn) {
        unsigned long long mykey = skey[tid];
        int rank = 0;
        for (int j = 0; j < cn; ++j)          // wave-uniform j -> LDS broadcast
            rank += (skey[j] < mykey) ? 1 : 0;
        ssx[rank] = scx[tid];
        ssy[rank] = scy[tid];
        sid[rank] = (int)(unsigned)(mykey & 0xffffffffu);
    }
    __syncthreads();

    if (tid < 64) {
        // ---- Phase B (wave 0): online front-to-back composite weights ----
        const int col = tid & 31, r = tid >> 5;
        const float pcx = 1.0f - (2.0f * (float)(X0 + col) + 1.0f) / (float)SS;
        const float pcy = 1.0f - (2.0f * (float)(Y0 + r) + 1.0f) / (float)SS;
        float T = 1.0f;
        int cnt = 0;
        for (int i = 0; i < cn; ++i) {
            float dx = pcx - ssx[i];          // broadcast LDS reads
            float dy = pcy - ssy[i];
            float d2 = dy * dy + dx * dx;     // ref op order (dy2+dx2)
            if (d2 < R2f && cnt < KK) {
                float dn = d2 / R2f;          // ref: dist_sel / RADIUS_NDC**2
                dn = fminf(fmaxf(dn, 0.001f), 1.0f);
                float a = 1.0f - sqrtf(dn);   // tau = 1
                sW[cnt * 64 + tid] = a * T;
                sS[cnt * 64 + tid] = i;       // sorted slot
                T *= (1.0f - a);
                ++cnt;
            }
        }
    } else {
        // ---- Phase G (waves 1-3): gather candidate features into LDS ----
        // thread -> (point stride 6, channel tid&31); per wave: 2 points x 32 ch.
        const int lc = tid & 31;
        const float* F = src + ((size_t)b * CC + half * 32 + lc) * NN;
        for (int s = (tid - 64) >> 5; s < cn; s += 6) {
            sF[s * FPAD + lc] = F[sid[s]];
        }
    }
    __syncthreads();

    // ---- Phase C: weighted accumulate from LDS + coalesced store ----
    const int px = tid & 63;
    const int cg = tid >> 6;                  // 0..3 -> 8 channels each
    float w[KK]; int sl[KK];
#pragma unroll
    for (int k = 0; k < KK; ++k) {
        w[k]  = sW[k * 64 + px];              // stride-1 lanes: conflict-free
        sl[k] = sS[k * 64 + px];
    }
    const int col = px & 31, r = px >> 5;
    float* O = out + (size_t)b * CC * (SS * SS) + (size_t)(Y0 + r) * SS + (X0 + col);
#pragma unroll
    for (int cc = 0; cc < 8; ++cc) {
        int lc = cg * 8 + cc;                 // local channel 0..31
        float acc = 0.0f;
#pragma unroll
        for (int k = 0; k < KK; ++k)
            acc += w[k] * sF[sl[k] * FPAD + lc];   // banks (slot+lc)%32: distinct
        O[(size_t)(half * 32 + lc) * (SS * SS)] = acc;  // 2x32 floats = 128B segs
    }
}

extern "C" void kernel_launch(void* const* d_in, const int* in_sizes, int n_in,
                              void* d_out, int out_size, void* d_ws, size_t ws_size,
                              hipStream_t stream) {
    const float* pts3D = (const float*)d_in[0]; // [2,2048,3]
    const float* src   = (const float*)d_in[1]; // [2,64,2048]
    float* out = (float*)d_out;                 // [2,64,128,128]
    (void)in_sizes; (void)n_in; (void)out_size; (void)d_ws; (void)ws_size;

    raster_fused_kernel<<<dim3(1024), dim3(256), 0, stream>>>(pts3D, src, out);
}

// Round 6
// 65.459 us; speedup vs baseline: 1.5944x; 1.0020x over previous
//
#include <hip/hip_runtime.h>
#include <math.h>

#define NN 2048
#define CC 64
#define SS 128
#define KK 8
#define TCAP 128   /* candidate cap per 2x32 tile; E[cn]~22, P(overflow)~0 */
#define FPAD 36    /* slot stride 144B: 16B-aligned for b128; banks (4s+c)%32 */

// RADIUS_NDC = 1.5/128*2 = 3/128 (exact dyadic); R2 = 9/16384 (exact dyadic)
#define R2f    0.00054931640625f
#define RNDCf  0.0234375f

// Fused raster+composite. Tile = 2 rows x 32 cols; each tile handled by TWO
// blocks (channel halves). Grid = 1024: blk = b(1)|ty(6)|tx(2)|half(1).
//   A: bbox-bin points into LDS (atomic append, unordered)
//   S: rank-sort candidates by u64 (z_bits, idx) key (unique -> total order ==
//      jax.lax.top_k smallest-z / lowest-index-tie order)
//   B (wave 0): per-pixel online front-to-back pass — first 8 strict d2<R2
//      hits in ascending-key order ARE the top-8; transmittance online.
//      Writes packed (w, slot) float2; zero-fills tail slots per pixel.
//   G (waves 1-3, concurrent with B): gather candidate feature rows into LDS.
//   C: weighted accumulate — 8 x ds_read_b64 (w,slot) + 16 x ds_read_b128
//      (features) per thread; coalesced 128B-segment stores.
__global__ __launch_bounds__(256, 4) void raster_fused_kernel(
    const float* __restrict__ pts3D,  // [B, N, 3]
    const float* __restrict__ src,    // [B, C, N]
    float* __restrict__ out)          // [B, C, S, S]
{
    __shared__ float scx[TCAP], scy[TCAP];
    __shared__ unsigned long long skey[TCAP];
    __shared__ float ssx[TCAP], ssy[TCAP];
    __shared__ int   sid[TCAP];            // sorted slot -> global point idx
    __shared__ int   scount;
    __shared__ float2 sWS[KK * 64];        // (w, slot bits) per (k, pixel)
    __shared__ alignas(16) float sF[TCAP * FPAD];  // candidate features (32 ch)

    const int tid  = threadIdx.x;
    const int blk  = blockIdx.x;           // 1024
    const int half = blk & 1;              // channels [half*32, half*32+32)
    const int X0   = ((blk >> 1) & 3) * 32;
    const int Y0   = ((blk >> 3) & 63) * 2;
    const int b    = blk >> 9;

    if (tid == 0) scount = 0;
    __syncthreads();

    // ---- Phase A: bin points whose 1.5px disk can touch this tile ----
    // pixel centers p(i) = 1 - (2i+1)/128 (exact dyadic), decreasing in i.
    // bbox as center+halfwidth: cols X0..X0+31 -> cx = 1-(2*X0+32)/128, rx=31/128
    //                           rows Y0..Y0+1  -> cy = 1-(2*Y0+2)/128,  ry=1/128
    const float cxc = 1.0f - (2.0f * (float)X0 + 32.0f) / 128.0f;
    const float cyc_ = 1.0f - (2.0f * (float)Y0 + 2.0f) / 128.0f;
    const float rx = 31.0f / 128.0f + RNDCf + 1e-6f;  // strict d2<R2 authoritative
    const float ry = 1.0f / 128.0f + RNDCf + 1e-6f;

    const float* P = pts3D + (size_t)b * NN * 3;
#pragma unroll
    for (int j = 0; j < NN / 256; ++j) {
        int n = tid + j * 256;
        float x = -P[n * 3 + 0], y = -P[n * 3 + 1], z = P[n * 3 + 2];
        if (z > 0.0f && fabsf(x - cxc) <= rx && fabsf(y - cyc_) <= ry) {
            int slot = atomicAdd(&scount, 1);
            if (slot < TCAP) {
                scx[slot] = x;
                scy[slot] = y;
                skey[slot] = ((unsigned long long)__float_as_uint(z) << 32) | (unsigned)n;
            }
        }
    }
    __syncthreads();
    const int cn = min(scount, TCAP);

    // ---- cn==0: block-uniform early out (never multiply w=0 by stale LDS) ----
    if (cn == 0) {
        const int px = tid & 63, cg = tid >> 6;
        const int col = px & 31, r = px >> 5;
        float* O = out + (size_t)b * CC * (SS * SS) + (size_t)(Y0 + r) * SS + (X0 + col);
#pragma unroll
        for (int cc = 0; cc < 8; ++cc)
            O[(size_t)(half * 32 + cg * 8 + cc) * (SS * SS)] = 0.0f;
        return;
    }

    // ---- Phase S: rank-sort by key ascending (keys unique -> bijective) ----
    if (tid < cn) {
        unsigned long long mykey = skey[tid];
        int rank = 0;
        for (int j = 0; j < cn; ++j)           // wave-uniform j -> LDS broadcast
            rank += (skey[j] < mykey) ? 1 : 0;
        ssx[rank] = scx[tid];
        ssy[rank] = scy[tid];
        sid[rank] = (int)(unsigned)(mykey & 0xffffffffu);
    }
    __syncthreads();

    if (tid < 64) {
        // ---- Phase B (wave 0): online front-to-back composite weights ----
        const int col = tid & 31, r = tid >> 5;
        const float pcx = 1.0f - (2.0f * (float)(X0 + col) + 1.0f) / 128.0f;
        const float pcy = 1.0f - (2.0f * (float)(Y0 + r) + 1.0f) / 128.0f;
        float T = 1.0f;
        int cnt = 0;
        for (int i = 0; i < cn; ++i) {
            float dx = pcx - ssx[i];           // broadcast LDS reads
            float dy = pcy - ssy[i];
            float d2 = dy * dy + dx * dx;      // ref op order (dy2+dx2)
            if (d2 < R2f && cnt < KK) {
                float dn = d2 / R2f;           // ref: dist_sel / RADIUS_NDC**2
                dn = fminf(fmaxf(dn, 0.001f), 1.0f);
                float a = 1.0f - sqrtf(dn);    // tau = 1
                sWS[cnt * 64 + tid] = make_float2(a * T, __int_as_float(i));
                T *= (1.0f - a);
                ++cnt;
            }
        }
        for (; cnt < KK; ++cnt)                // tail: w=0, slot=0 (sF[0] valid, cn>0)
            sWS[cnt * 64 + tid] = make_float2(0.0f, __int_as_float(0));
    } else {
        // ---- Phase G (waves 1-3): gather candidate feature rows into LDS ----
        const int lc = tid & 31;               // local channel
        const float* F = src + ((size_t)b * CC + half * 32 + lc) * NN;
        for (int s = (tid - 64) >> 5; s < cn; s += 6)
            sF[s * FPAD + lc] = F[sid[s]];     // banks (4s+lc)%32: conflict-free
    }
    __syncthreads();

    // ---- Phase C: weighted accumulate from LDS + coalesced store ----
    const int px = tid & 63;
    const int cg = tid >> 6;                   // 0..3 -> 8 channels each
    float w[KK]; int sl[KK];
#pragma unroll
    for (int k = 0; k < KK; ++k) {
        float2 ws = sWS[k * 64 + px];          // ds_read_b64, stride-1 lanes
        w[k]  = ws.x;
        sl[k] = __float_as_int(ws.y);
    }
    const int col = px & 31, r = px >> 5;
    float* O = out + (size_t)b * CC * (SS * SS) + (size_t)(Y0 + r) * SS + (X0 + col);
#pragma unroll
    for (int g = 0; g < 2; ++g) {
        float4 acc = make_float4(0.0f, 0.0f, 0.0f, 0.0f);
#pragma unroll
        for (int k = 0; k < KK; ++k) {         // ds_read_b128; same-slot lanes broadcast
            const float4 f = *reinterpret_cast<const float4*>(
                &sF[sl[k] * FPAD + cg * 8 + g * 4]);
            acc.x += w[k] * f.x;
            acc.y += w[k] * f.y;
            acc.z += w[k] * f.z;
            acc.w += w[k] * f.w;
        }
        const int c0 = half * 32 + cg * 8 + g * 4;
        O[(size_t)(c0 + 0) * (SS * SS)] = acc.x;   // 2 rows x 32 px = 128B segs
        O[(size_t)(c0 + 1) * (SS * SS)] = acc.y;
        O[(size_t)(c0 + 2) * (SS * SS)] = acc.z;
        O[(size_t)(c0 + 3) * (SS * SS)] = acc.w;
    }
}

extern "C" void kernel_launch(void* const* d_in, const int* in_sizes, int n_in,
                              void* d_out, int out_size, void* d_ws, size_t ws_size,
                              hipStream_t stream) {
    const float* pts3D = (const float*)d_in[0]; // [2,2048,3]
    const float* src   = (const float*)d_in[1]; // [2,64,2048]
    float* out = (float*)d_out;                 // [2,64,128,128]
    (void)in_sizes; (void)n_in; (void)out_size; (void)d_ws; (void)ws_size;

    raster_fused_kernel<<<dim3(1024), dim3(256), 0, stream>>>(pts3D, src, out);
}